// Round 1
// 128.367 us; speedup vs baseline: 1.0558x; 1.0558x over previous
//
#include <hip/hip_runtime.h>
#include <stdint.h>

// DepthAwareConv2d: out = conv2d(x * depth, weight, pad=1) + bias
// (depth is channel-independent, so the depth-modulated im2col GEMM factors
//  into a plain 3x3 conv of xd = x*depth).
//
// R7 = R6 + latency-hiding restructure of both kernels.
//  conv: double-buffered x strip LDS (2x33,280B); next-phase global_load_lds
//        chunks issued spread across the 9 taps AFTER each tap's a-prefetch
//        (FIFO vmcnt: areg waits never drain stage chunks). One barrier per
//        phase boundary. wt2 repacked so each a-frag load is a contiguous
//        1KB wave load. s_setprio(1) around the MFMA cluster.
//  prep: 1024 half-row blocks (n,y,h: 64 channels each). Phase 1 writes the
//        transpose INTO LDS as dwords (channel pairs, ~2-way conflicts);
//        phase 2 reads ds_read_b128 and stores dwordx4 (16B/lane).

#define C_IN 128
#define O_OUT 256
#define HW 128
#define NB 4
#define PADW 130

#define XD_ELEMS ((size_t)NB * PADW * PADW * C_IN)
#define XD_BYTES (XD_ELEMS * 2)          // 17,305,600 B
#define WT_ELEMS ((size_t)O_OUT * C_IN * 9)
#define WT_BYTES (WT_ELEMS * 2)          // 589,824 B

typedef __attribute__((ext_vector_type(8))) short short8;  // 8 bf16 (4 VGPRs)
typedef __attribute__((ext_vector_type(4))) float f32x4;
typedef __attribute__((ext_vector_type(2))) float f32x2;
typedef __attribute__((ext_vector_type(4))) unsigned uint4v;

__device__ __forceinline__ unsigned f2bf_bits(float f) {
  unsigned u = __builtin_bit_cast(unsigned, f);
  return (u + 0x7fffu + ((u >> 16) & 1u)) >> 16;   // RNE, inputs finite
}

__device__ __forceinline__ void async_load16(const void* g, void* l) {
  __builtin_amdgcn_global_load_lds(
      (__attribute__((address_space(1))) void*)g,
      (__attribute__((address_space(3))) void*)l, 16, 0, 0);
}

// ---- prep (single dispatch): xd rows + halo + weight frag-relayout ---------
// Blocks 0..1023  : one (n,y,h) half-row (64 channels). Coalesced f32x2 reads
//                   of x (2 channels/iter), scale by depth, dword scatter into
//                   LDS in output layout, then b128 reads + dwordx4 stores.
// Blocks 1024..1027: zero halo rows 0 and 129 of image n.
// Blocks 1028..1091: wt2 in MFMA-A-fragment order, contiguous per (s,wm,t):
//   gid = o0*147456 + s*4096 + wm*2048 + t*512 + lane*8 + j   (shorts)
//   o = o0*128 + wm*64 + t*16 + (lane&15)
//   cc = s/9; tap = s%9; c = cc*32 + (lane>>4)*8 + j
__global__ __launch_bounds__(256) void prep_all(const float* __restrict__ x,
                                                const float* __restrict__ depth,
                                                const float* __restrict__ w,
                                                short* __restrict__ xd,
                                                short* __restrict__ wt2) {
  const int R = blockIdx.x;
  const int tid = threadIdx.x;

  if (R >= NB * HW * 2 + NB) {              // ---- weight blocks
    int gid = (R - (NB * HW * 2 + NB)) * 4608 + tid;   // 64 * 4608 = 294912
#pragma unroll
    for (int i = 0; i < 18; ++i, gid += 256) {
      const int j = gid & 7;
      const int lane = (gid >> 3) & 63;
      const int t = (gid >> 9) & 3;
      const int wm = (gid >> 11) & 1;
      const int g2 = gid >> 12;
      const int s = g2 % 36;               // K-slot in conv order: cc*9 + tap
      const int o0 = g2 / 36;
      const int ln = lane & 15, q = lane >> 4;
      const int o = (o0 << 7) + (wm << 6) + (t << 4) + ln;
      const int cc = s / 9;
      const int tap = s % 9;
      const int c = (cc << 5) + (q << 3) + j;
      wt2[gid] = (short)f2bf_bits(w[((size_t)o * C_IN + c) * 9 + tap]);
    }
    return;
  }

  if (R >= NB * HW * 2) {                   // ---- halo-row zero blocks
    const int n = R - NB * HW * 2;
    uint4v* base0 = (uint4v*)(xd + (size_t)n * PADW * PADW * C_IN);
    uint4v* base1 = (uint4v*)(xd + ((size_t)n * PADW + (PADW - 1)) * PADW * C_IN);
    const uint4v z = {0u, 0u, 0u, 0u};
    const int per_row = PADW * C_IN * 2 / 16;   // 2080 uint4 per padded row
    for (int i = tid; i < per_row; i += 256) {
      base0[i] = z;
      base1[i] = z;
    }
    return;
  }

  // ---- half-row transform blocks: channels h*64..h*64+63 of row (n,y)
  // LDS layout: s32[px 0..127][36 dwords] (stride 36 keeps b128 16B-aligned;
  // cp slot 0..31 = channel pair within the 64-ch half).
  __shared__ __align__(16) unsigned s32[HW * 36];   // 18,432 B

  const int n = R >> 8;
  const int y = (R >> 1) & 127;
  const int h = R & 1;
  const int lane = tid & 63;
  const int wave = tid >> 6;

  // zero this half's 32 dwords of the two edge pixels (x=0 and x=129)
  {
    unsigned* row = (unsigned*)(xd + (size_t)(n * PADW + y + 1) * PADW * C_IN);
    if (tid < 32) row[(h << 5) + tid] = 0u;
    else if (tid < 64) row[(size_t)(PADW - 1) * 64 + (h << 5) + (tid - 32)] = 0u;
  }

  // phase 1: read 2 channels per iter (f32x2, coalesced), scale by depth,
  // scatter channel-pair dwords into LDS output layout (~2-way conflicts).
  const f32x2 d2 = *(const f32x2*)(depth + ((size_t)n * HW + y) * HW + 2 * lane);
  const float* xrow =
      x + (((size_t)(n * C_IN + (h << 6)) * HW) + y) * HW + 2 * lane;
#pragma unroll
  for (int it = 0; it < 8; ++it) {
    const int cp = (wave << 3) + it;        // 0..31
    const f32x2 va = *(const f32x2*)(xrow + (size_t)(2 * cp) * HW * HW);
    const f32x2 vb = *(const f32x2*)(xrow + (size_t)(2 * cp + 1) * HW * HW);
    s32[(2 * lane) * 36 + cp] =
        f2bf_bits(va.x * d2.x) | (f2bf_bits(vb.x * d2.x) << 16);
    s32[(2 * lane + 1) * 36 + cp] =
        f2bf_bits(va.y * d2.y) | (f2bf_bits(vb.y * d2.y) << 16);
  }
  __syncthreads();

  // phase 2: b128 reads + dwordx4 stores (pixels 1..128, this channel half)
  unsigned* orow = (unsigned*)(xd + ((size_t)(n * PADW + y + 1) * PADW + 1) * C_IN);
#pragma unroll
  for (int i = 0; i < 4; ++i) {
    const int flat = tid + (i << 8);        // 0..1023
    const int px = flat >> 3, jj = flat & 7;
    const uint4v v = *(const uint4v*)&s32[px * 36 + (jj << 2)];
    *(uint4v*)&orow[(size_t)px * 64 + (h << 5) + (jj << 2)] = v;
  }
}

// ---- main MFMA implicit-GEMM conv ------------------------------------------
// Block: 256 threads (4 waves, 2x2), tile 128(o) x 256(px = 2 output rows).
// Wave tile 64(o) x 128(px): acc 4x8. K = 1152 as (cc 0..3) x (tap 0..8).
// Double-buffered strips: while the 9 taps of phase cc compute out of
// xbuf[cc&1], the strip for cc+1 streams into xbuf[(cc+1)&1] one 16B-chunk-
// per-thread per tap (issued AFTER the tap's a-prefetch so the compiler's
// areg vmcnt waits never force the stage chunks to drain). One barrier per
// phase boundary (4 total); its vmcnt(0) is reached with ~9 taps of slack.
__global__ __launch_bounds__(256, 2) void conv_mfma(
    const short* __restrict__ xd, const short* __restrict__ wt2,
    const float* __restrict__ bias, float* __restrict__ out) {
  __shared__ __align__(16) short xbuf[2][16640];   // 2 x [px_strip 520][32 ch]

  const int tid = threadIdx.x;
  const int bx = blockIdx.x;            // n*64 + ypair
  const int n = bx >> 6;
  const int y = (bx & 63) << 1;         // first of two output rows
  const int o0b = blockIdx.y;           // o tile (x128)
  const int lane = tid & 63;
  const int wave = tid >> 6;
  const int wm = wave & 1, wn = wave >> 1;
  const int ln = lane & 15, q = lane >> 4;

  // W fragment stream base (shorts): each (s,t) frag is a contiguous 1KB
  const short* wbase = wt2 + (size_t)o0b * 147456 + (wm << 11) + (lane << 3);

  // X strip staging: strip = padded rows y..y+3, px 0..129, chunk f=0..2079
  // src(f) = strip_base + (f>>2)*128 + cc*32 + (f&3)*8 ; lds(f) = f*8
  const short* xsrc0 = xd + (size_t)(n * PADW + y) * PADW * C_IN +
                       (tid >> 2) * C_IN + (tid & 3) * 8;

  f32x4 acc[4][8] = {};
  short8 areg[2][4];

  auto loadA = [&](int s, int p) {
#pragma unroll
    for (int t = 0; t < 4; ++t)
      areg[p][t] = *(const short8*)(wbase + (size_t)s * 4096 + t * 512);
  };

  {  // prologue: stage strip cc=0 into buf0
    short* xdst = &xbuf[0][0] + tid * 8;
#pragma unroll
    for (int j = 0; j < 8; ++j)
      async_load16(xsrc0 + j * 8192, xdst + j * 2048);
    if (tid < 32) async_load16(xsrc0 + 8 * 8192, xdst + 8 * 2048);
  }
  loadA(0, 0);
  __syncthreads();   // buf0 ready

#pragma unroll
  for (int cc = 0; cc < 4; ++cc) {
#pragma unroll
    for (int tap = 0; tap < 9; ++tap) {
      const int s = cc * 9 + tap;
      if (s + 1 < 36) loadA(s + 1, (s + 1) & 1);   // prefetch next a-frags

      if (cc + 1 < 4) {   // spread next-strip staging across taps (after loadA!)
        const short* sp = xsrc0 + ((cc + 1) << 5);
        short* xdst = &xbuf[(cc + 1) & 1][0] + tid * 8;
        if (tap < 8) async_load16(sp + tap * 8192, xdst + tap * 2048);
        if (tap == 0 && tid < 32)
          async_load16(sp + 8 * 8192, xdst + 8 * 2048);  // tail 32 chunks
      }

      const int ti = tap / 3, tj = tap % 3;        // static under unroll
      const int rbase = (wn + ti) * 130 + tj;      // strip row + col shift

      short8 b[8];
#pragma unroll
      for (int u = 0; u < 8; ++u)
        b[u] = *(const short8*)(&xbuf[cc & 1][0] +
                                (rbase + (u << 4) + ln) * 32 + (q << 3));
      __builtin_amdgcn_s_setprio(1);
#pragma unroll
      for (int t = 0; t < 4; ++t)
#pragma unroll
        for (int u = 0; u < 8; ++u)
          acc[t][u] = __builtin_amdgcn_mfma_f32_16x16x32_bf16(
              areg[s & 1][t], b[u], acc[t][u], 0, 0, 0);
      __builtin_amdgcn_s_setprio(0);
    }
    if (cc + 1 < 4) __syncthreads();   // buf(cc+1) staged+drained; buf(cc) free
  }

  // epilogue: D layout col=lane&15 (pixel), row=q*4+r (o)
#pragma unroll
  for (int t = 0; t < 4; ++t) {
    const int ob = (o0b << 7) + (wm << 6) + (t << 4) + (q << 2);
#pragma unroll
    for (int u = 0; u < 8; ++u) {
      const int xcol = (u << 4) + ln;           // 0..127
      const int yrow = y + wn;
#pragma unroll
      for (int r = 0; r < 4; ++r) {
        const int o = ob + r;
        out[(((size_t)n * O_OUT + o) * HW + yrow) * HW + xcol] =
            acc[t][u][r] + bias[o];
      }
    }
  }
}

// ---- fallback (only if ws_size is too small): naive direct conv ------------
__global__ void conv_naive(const float* __restrict__ x,
                           const float* __restrict__ depth,
                           const float* __restrict__ w,
                           const float* __restrict__ bias,
                           float* __restrict__ out) {
  const int gid = blockIdx.x * 256 + threadIdx.x;
  if (gid >= NB * O_OUT * HW * HW) return;
  const int xc = gid & 127;
  const int y = (gid >> 7) & 127;
  const int o = (gid >> 14) & 255;
  const int n = gid >> 22;
  float s = bias[o];
  for (int c = 0; c < C_IN; ++c)
    for (int i = 0; i < 3; ++i) {
      const int yy = y + i - 1;
      if (yy < 0 || yy >= HW) continue;
      for (int j = 0; j < 3; ++j) {
        const int xx = xc + j - 1;
        if (xx < 0 || xx >= HW) continue;
        s += w[((o * C_IN + c) * 3 + i) * 3 + j] *
             x[(((size_t)n * C_IN + c) * HW + yy) * HW + xx] *
             depth[((size_t)n * HW + yy) * HW + xx];
      }
    }
  out[gid] = s;
}

extern "C" void kernel_launch(void* const* d_in, const int* in_sizes, int n_in,
                              void* d_out, int out_size, void* d_ws, size_t ws_size,
                              hipStream_t stream) {
  const float* x = (const float*)d_in[0];
  const float* depth = (const float*)d_in[1];
  // d_in[2] = camera_params (unused by reference)
  const float* weight = (const float*)d_in[3];
  const float* bias = (const float*)d_in[4];
  float* out = (float*)d_out;

  const size_t need = XD_BYTES + WT_BYTES;
  if (ws_size < need) {
    conv_naive<<<(NB * O_OUT * HW * HW + 255) / 256, 256, 0, stream>>>(
        x, depth, weight, bias, out);
    return;
  }

  short* xd = (short*)d_ws;
  short* wt2 = (short*)((char*)d_ws + XD_BYTES);

  prep_all<<<NB * HW * 2 + NB + 64, 256, 0, stream>>>(x, depth, weight, xd, wt2);
  conv_mfma<<<dim3(NB * HW / 2, 2), 256, 0, stream>>>(xd, wt2, bias, out);
}